// Round 2
// baseline (875.349 us; speedup 1.0000x reference)
//
#include <hip/hip_runtime.h>
#include <hip/hip_cooperative_groups.h>
#include <math.h>

namespace cg = cooperative_groups;

#define HID 768
#define NB 64
#define NL 8
#define SEQ 512
#define G4 3072   // 4*HID

__device__ __forceinline__ float sigmoid_(float x) { return 1.0f / (1.0f + expf(-x)); }
__device__ __forceinline__ float gelu_(float x) { return 0.5f * x * (1.0f + erff(x * 0.70710678118654752440f)); }

// ---------------------------------------------------------------------------
// K1: decode sep_by indices (handles int64 or int32 payload)
// ---------------------------------------------------------------------------
__global__ void decode_idx_kernel(const void* __restrict__ sep_by, int n, int* __restrict__ out) {
    const int* p32 = (const int*)sep_by;
    // sep_by values are in [1, SEQ): if stored as little-endian int64 the odd
    // 32-bit words are all zero; if int32, they are random nonzero values.
    const bool is64 = (p32[1] == 0) && (p32[3] == 0) && (p32[5] == 0) && (p32[7] == 0);
    int i = blockIdx.x * blockDim.x + threadIdx.x;
    if (i < n) {
        out[i] = is64 ? (int)((const long long*)sep_by)[i] : p32[i];
    }
}

// ---------------------------------------------------------------------------
// K2: xg = gather(sep_emb) @ w_ih^T + b_ih + b_hh, both directions.
// M=512 (b*8+t in scan order), N=3072, K=768.  64x64 tile, BK=16, 4x4/thread.
// grid = 48x8x2 = 768 blocks = exactly 3 blocks/CU.
// ---------------------------------------------------------------------------
__global__ __launch_bounds__(256) void xg_gemm_kernel(
    const float* __restrict__ electra, const int* __restrict__ idx,
    const float* __restrict__ w_ih_f, const float* __restrict__ w_ih_b,
    const float* __restrict__ b_ih_f, const float* __restrict__ b_hh_f,
    const float* __restrict__ b_ih_b, const float* __restrict__ b_hh_b,
    float* __restrict__ xg_f, float* __restrict__ xg_b)
{
    const int dir = blockIdx.z;
    const float* Wt = dir ? w_ih_b : w_ih_f;
    const float* BI = dir ? b_ih_b : b_ih_f;
    const float* BH = dir ? b_hh_b : b_hh_f;
    float* XG = dir ? xg_b : xg_f;
    const int mt = blockIdx.y;   // 0..7
    const int nt = blockIdx.x;   // 0..47

    __shared__ float As[16][68];  // [k][m], +4 pad (2-way LDS alias only = free)
    __shared__ float Bs[16][68];  // [k][n]

    const int tid = threadIdx.x;
    const int tx = tid & 15, ty = tid >> 4;
    const int lr = tid >> 2;          // 0..63 row within tile
    const int lk = (tid & 3) << 2;    // 0,4,8,12

    // A row: m = b*8 + t (t = scan step). backward uses reversed time.
    const int m = mt * 64 + lr;
    const int bb = m >> 3, t = m & 7;
    const int tt = dir ? (7 - t) : t;
    const int row = idx[bb * 8 + tt];
    const float* Aptr = electra + ((size_t)bb * SEQ + row) * HID + lk;
    const float* Bptr = Wt + (size_t)(nt * 64 + lr) * HID + lk;

    float acc[4][4] = {};
    for (int k0 = 0; k0 < HID; k0 += 16) {
        const float4 a4 = *(const float4*)(Aptr + k0);
        const float4 b4 = *(const float4*)(Bptr + k0);
        __syncthreads();
        As[lk + 0][lr] = a4.x; As[lk + 1][lr] = a4.y; As[lk + 2][lr] = a4.z; As[lk + 3][lr] = a4.w;
        Bs[lk + 0][lr] = b4.x; Bs[lk + 1][lr] = b4.y; Bs[lk + 2][lr] = b4.z; Bs[lk + 3][lr] = b4.w;
        __syncthreads();
#pragma unroll
        for (int k = 0; k < 16; ++k) {
            const float4 av = *(const float4*)&As[k][ty << 2];
            const float4 bv = *(const float4*)&Bs[k][tx << 2];
            acc[0][0] = fmaf(av.x, bv.x, acc[0][0]);
            acc[0][1] = fmaf(av.x, bv.y, acc[0][1]);
            acc[0][2] = fmaf(av.x, bv.z, acc[0][2]);
            acc[0][3] = fmaf(av.x, bv.w, acc[0][3]);
            acc[1][0] = fmaf(av.y, bv.x, acc[1][0]);
            acc[1][1] = fmaf(av.y, bv.y, acc[1][1]);
            acc[1][2] = fmaf(av.y, bv.z, acc[1][2]);
            acc[1][3] = fmaf(av.y, bv.w, acc[1][3]);
            acc[2][0] = fmaf(av.z, bv.x, acc[2][0]);
            acc[2][1] = fmaf(av.z, bv.y, acc[2][1]);
            acc[2][2] = fmaf(av.z, bv.z, acc[2][2]);
            acc[2][3] = fmaf(av.z, bv.w, acc[2][3]);
            acc[3][0] = fmaf(av.w, bv.x, acc[3][0]);
            acc[3][1] = fmaf(av.w, bv.y, acc[3][1]);
            acc[3][2] = fmaf(av.w, bv.z, acc[3][2]);
            acc[3][3] = fmaf(av.w, bv.w, acc[3][3]);
        }
    }

    const int nbase = nt * 64 + (tx << 2);
    const float4 bi = *(const float4*)&BI[nbase];
    const float4 bh = *(const float4*)&BH[nbase];
    const float4 bias = {bi.x + bh.x, bi.y + bh.y, bi.z + bh.z, bi.w + bh.w};
#pragma unroll
    for (int i = 0; i < 4; ++i) {
        const int mrow = mt * 64 + (ty << 2) + i;
        float4 o;
        o.x = acc[i][0] + bias.x; o.y = acc[i][1] + bias.y;
        o.z = acc[i][2] + bias.z; o.w = acc[i][3] + bias.w;
        *(float4*)&XG[(size_t)mrow * G4 + nbase] = o;
    }
}

// ---------------------------------------------------------------------------
// K3: cooperative LSTM recurrence, both directions, 8 steps, c in registers.
// grid = 256 blocks (dir 2 x btile 4 x jtile 32) x 384 threads (16b x 24j)
// = exactly 1 block / CU, 6 waves / CU, perfectly balanced across grid syncs.
// Hbuf: [parity][dir][b][j] ping-pong; Hfirst: [dir][b][j] (h after step 0).
// ---------------------------------------------------------------------------
__global__ __launch_bounds__(384) void lstm_rec_kernel(
    const float* __restrict__ whh_f, const float* __restrict__ whh_b,
    const float* __restrict__ xg_f, const float* __restrict__ xg_b,
    float* __restrict__ Hbuf, float* __restrict__ Hfirst)
{
    cg::grid_group grid = cg::this_grid();
    const int bid = blockIdx.x;
    const int dir = bid >> 7;            // 0..1
    const int rem = bid & 127;
    const int btile = rem >> 5;          // 0..3  (16 batches each)
    const int jtile = rem & 31;          // 0..31 (24 j each)
    const float* WHH = dir ? whh_b : whh_f;
    const float* XG  = dir ? xg_b : xg_f;
    const int tid = threadIdx.x;
    const int bl = tid & 15, jl = tid >> 4;   // jl 0..23
    const int b = btile * 16 + bl;
    const int j = jtile * 24 + jl;

    const float4* wi4 = (const float4*)(WHH + (size_t)(0 * HID + j) * HID);
    const float4* wf4 = (const float4*)(WHH + (size_t)(1 * HID + j) * HID);
    const float4* wg4 = (const float4*)(WHH + (size_t)(2 * HID + j) * HID);
    const float4* wo4 = (const float4*)(WHH + (size_t)(3 * HID + j) * HID);

    __shared__ float Hs[16][772];   // +4 pad: b128 reads alias only 2-way (free)

    float c = 0.0f;
    const size_t dslot = ((size_t)dir * NB + b) * HID + j;
    if (bl == 0 || jl < 24) Hbuf[dslot] = 0.0f;  // parity-0 init (all threads)
    grid.sync();

    for (int s = 0; s < 8; ++s) {
        const int cur = s & 1;
        const float* Hcur = Hbuf + (size_t)cur * (2 * NB * HID) + (size_t)dir * NB * HID
                          + (size_t)btile * 16 * HID;
        for (int q = tid; q < 16 * 192; q += 384) {
            const int r = q / 192, c4 = q % 192;
            *(float4*)&Hs[r][c4 << 2] = *(const float4*)(Hcur + r * HID + (c4 << 2));
        }
        __syncthreads();

        float ai0 = 0.f, af0 = 0.f, ag0 = 0.f, ao0 = 0.f;
        float ai1 = 0.f, af1 = 0.f, ag1 = 0.f, ao1 = 0.f;
        const float4* h4 = (const float4*)&Hs[bl][0];
#pragma unroll 4
        for (int k4 = 0; k4 < 192; k4 += 2) {
            {
                const float4 h = h4[k4];
                const float4 a = wi4[k4], f = wf4[k4], g = wg4[k4], o = wo4[k4];
                ai0 = fmaf(h.x, a.x, fmaf(h.y, a.y, fmaf(h.z, a.z, fmaf(h.w, a.w, ai0))));
                af0 = fmaf(h.x, f.x, fmaf(h.y, f.y, fmaf(h.z, f.z, fmaf(h.w, f.w, af0))));
                ag0 = fmaf(h.x, g.x, fmaf(h.y, g.y, fmaf(h.z, g.z, fmaf(h.w, g.w, ag0))));
                ao0 = fmaf(h.x, o.x, fmaf(h.y, o.y, fmaf(h.z, o.z, fmaf(h.w, o.w, ao0))));
            }
            {
                const float4 h = h4[k4 + 1];
                const float4 a = wi4[k4 + 1], f = wf4[k4 + 1], g = wg4[k4 + 1], o = wo4[k4 + 1];
                ai1 = fmaf(h.x, a.x, fmaf(h.y, a.y, fmaf(h.z, a.z, fmaf(h.w, a.w, ai1))));
                af1 = fmaf(h.x, f.x, fmaf(h.y, f.y, fmaf(h.z, f.z, fmaf(h.w, f.w, af1))));
                ag1 = fmaf(h.x, g.x, fmaf(h.y, g.y, fmaf(h.z, g.z, fmaf(h.w, g.w, ag1))));
                ao1 = fmaf(h.x, o.x, fmaf(h.y, o.y, fmaf(h.z, o.z, fmaf(h.w, o.w, ao1))));
            }
        }

        const float* xg = XG + ((size_t)b * NL + s) * G4 + j;
        const float gi = sigmoid_(ai0 + ai1 + xg[0]);
        const float gf = sigmoid_(af0 + af1 + xg[HID]);
        const float gg = tanhf (ag0 + ag1 + xg[2 * HID]);
        const float go = sigmoid_(ao0 + ao1 + xg[3 * HID]);
        c = gf * c + gi * gg;
        const float hn = go * tanhf(c);

        Hbuf[(size_t)(cur ^ 1) * (2 * NB * HID) + dslot] = hn;
        if (s == 0) Hfirst[dslot] = hn;
        grid.sync();
    }
}

// ---------------------------------------------------------------------------
// K4: head. sep_first = [h_f(t0), h_b(final)], sep_last = [h_f(final), h_b(t0)]
// x = gelu([cls, sep_first, sep_last]); out = x@fc1^T+b ; first/last = s@fc2^T+b
// ---------------------------------------------------------------------------
__device__ __forceinline__ void reduce10_(float* p, float* red, int tid,
                                          float* dst, const float* __restrict__ bias) {
#pragma unroll
    for (int o = 0; o < 10; ++o) {
        float v = p[o];
#pragma unroll
        for (int off = 32; off > 0; off >>= 1) v += __shfl_down(v, off);
        if ((tid & 63) == 0) red[o * 4 + (tid >> 6)] = v;
    }
    __syncthreads();
    if (tid < 10) dst[tid] = red[tid * 4 + 0] + red[tid * 4 + 1] + red[tid * 4 + 2] + red[tid * 4 + 3] + bias[tid];
    __syncthreads();
}

__global__ __launch_bounds__(256) void head_kernel(
    const float* __restrict__ electra, const float* __restrict__ Hbuf,
    const float* __restrict__ Hfirst,
    const float* __restrict__ fc1_w, const float* __restrict__ fc1_b,
    const float* __restrict__ fc2_w, const float* __restrict__ fc2_b,
    float* __restrict__ out)
{
    const int b = blockIdx.x;
    const int tid = threadIdx.x;
    __shared__ float xs[5 * HID];
    __shared__ float sf[2 * HID];
    __shared__ float sl[2 * HID];
    __shared__ float red[40];

    const float* hf0 = Hfirst + (size_t)b * HID;                        // h_fwd t=0
    const float* hb0 = Hfirst + (size_t)NB * HID + (size_t)b * HID;     // h_bwd step0
    const float* hff = Hbuf + (size_t)b * HID;                          // h_fwd final (parity 0, dir 0)
    const float* hbf = Hbuf + (size_t)NB * HID + (size_t)b * HID;       // h_bwd final

    for (int k = tid; k < HID; k += 256) {
        xs[k] = gelu_(electra[(size_t)b * SEQ * HID + k]);    // cls row (t=0)
        const float v1 = hf0[k]; sf[k] = v1;        xs[HID + k]     = gelu_(v1);
        const float v2 = hbf[k]; sf[HID + k] = v2;  xs[2 * HID + k] = gelu_(v2);
        const float v3 = hff[k]; sl[k] = v3;        xs[3 * HID + k] = gelu_(v3);
        const float v4 = hb0[k]; sl[HID + k] = v4;  xs[4 * HID + k] = gelu_(v4);
    }
    __syncthreads();

    {
        float p[10];
#pragma unroll
        for (int o = 0; o < 10; ++o) p[o] = 0.f;
        for (int k = tid; k < 5 * HID; k += 256) {
            const float xv = xs[k];
#pragma unroll
            for (int o = 0; o < 10; ++o) p[o] = fmaf(xv, fc1_w[o * (5 * HID) + k], p[o]);
        }
        reduce10_(p, red, tid, out + b * 10, fc1_b);
    }
    {
        float p[10];
#pragma unroll
        for (int o = 0; o < 10; ++o) p[o] = 0.f;
        for (int k = tid; k < 2 * HID; k += 256) {
            const float v = sf[k];
#pragma unroll
            for (int o = 0; o < 10; ++o) p[o] = fmaf(v, fc2_w[o * (2 * HID) + k], p[o]);
        }
        reduce10_(p, red, tid, out + 640 + b * 10, fc2_b);
    }
    {
        float p[10];
#pragma unroll
        for (int o = 0; o < 10; ++o) p[o] = 0.f;
        for (int k = tid; k < 2 * HID; k += 256) {
            const float v = sl[k];
#pragma unroll
            for (int o = 0; o < 10; ++o) p[o] = fmaf(v, fc2_w[o * (2 * HID) + k], p[o]);
        }
        reduce10_(p, red, tid, out + 1280 + b * 10, fc2_b);
    }
}

// ---------------------------------------------------------------------------
extern "C" void kernel_launch(void* const* d_in, const int* in_sizes, int n_in,
                              void* d_out, int out_size, void* d_ws, size_t ws_size,
                              hipStream_t stream) {
    const float* electra = (const float*)d_in[0];
    const void*  sep_by  = d_in[2];
    const float* w_ih_f  = (const float*)d_in[3];
    const float* w_hh_f  = (const float*)d_in[4];
    const float* b_ih_f  = (const float*)d_in[5];
    const float* b_hh_f  = (const float*)d_in[6];
    const float* w_ih_b  = (const float*)d_in[7];
    const float* w_hh_b  = (const float*)d_in[8];
    const float* b_ih_b  = (const float*)d_in[9];
    const float* b_hh_b  = (const float*)d_in[10];
    const float* fc1_w   = (const float*)d_in[11];
    const float* fc1_b   = (const float*)d_in[12];
    const float* fc2_w   = (const float*)d_in[13];
    const float* fc2_b   = (const float*)d_in[14];
    float* out = (float*)d_out;

    // workspace layout (bytes)
    char* ws = (char*)d_ws;
    int*   idx    = (int*)(ws);                                   // 2 KB
    float* xg_f   = (float*)(ws + 4096);                          // 6 MB
    float* xg_b   = (float*)(ws + 4096 + 6291456);                // 6 MB
    float* Hbuf   = (float*)(ws + 4096 + 2 * 6291456);            // 768 KB [2][2][64][768]
    float* Hfirst = (float*)(ws + 4096 + 2 * 6291456 + 786432);   // 384 KB [2][64][768]

    decode_idx_kernel<<<1, 512, 0, stream>>>(sep_by, NB * NL, idx);

    xg_gemm_kernel<<<dim3(48, 8, 2), 256, 0, stream>>>(
        electra, idx, w_ih_f, w_ih_b, b_ih_f, b_hh_f, b_ih_b, b_hh_b, xg_f, xg_b);

    {
        const float* a0 = w_hh_f; const float* a1 = w_hh_b;
        const float* a2 = xg_f;   const float* a3 = xg_b;
        float* a4 = Hbuf;         float* a5 = Hfirst;
        void* args[] = {&a0, &a1, &a2, &a3, &a4, &a5};
        hipLaunchCooperativeKernel((void*)lstm_rec_kernel, dim3(256), dim3(384),
                                   args, 0, stream);
    }

    head_kernel<<<64, 256, 0, stream>>>(electra, Hbuf, Hfirst,
                                        fc1_w, fc1_b, fc2_w, fc2_b, out);
}

// Round 5
// 542.548 us; speedup vs baseline: 1.6134x; 1.6134x over previous
//
#include <hip/hip_runtime.h>
#include <math.h>

#define HID 768
#define NB 64
#define NL 8
#define SEQ 512
#define G4 3072   // 4*HID

__device__ __forceinline__ float sigmoid_(float x) { return 1.0f / (1.0f + expf(-x)); }
__device__ __forceinline__ float gelu_(float x) { return 0.5f * x * (1.0f + erff(x * 0.70710678118654752440f)); }

// ---------------------------------------------------------------------------
// K1: decode sep_by indices (handles int64 or int32 payload)
// ---------------------------------------------------------------------------
__global__ void decode_idx_kernel(const void* __restrict__ sep_by, int n, int* __restrict__ out) {
    const int* p32 = (const int*)sep_by;
    const bool is64 = (p32[1] == 0) && (p32[3] == 0) && (p32[5] == 0) && (p32[7] == 0);
    int i = blockIdx.x * blockDim.x + threadIdx.x;
    if (i < n) {
        out[i] = is64 ? (int)((const long long*)sep_by)[i] : p32[i];
    }
}

// ---------------------------------------------------------------------------
// K2: xg^T[dir][n][m] = (gather A)[m] . w_ih[n] + b_ih[n] + b_hh[n]
// m = b*8 + s (scan order; dir=1 gathers time-reversed rows).
// Wave: lane = m-row (64 rows of one mt), 8 weight-row streams via the
// SCALAR pipe (wave-uniform bases). No LDS at all. Stores coalesced ([n][m]).
// grid = 48 x 8 x 2 = 768 blocks x 512 thr = 3 blocks/CU, 6 waves/SIMD.
// VALU-balanced: 6144 waves / 1024 SIMDs = 6 each; 768k*8n*2cyc*6 = 73.7K cyc.
// ---------------------------------------------------------------------------
__global__ __launch_bounds__(512) void xg_gemm_kernel(
    const float* __restrict__ electra, const int* __restrict__ idx,
    const float* __restrict__ w_ih_f, const float* __restrict__ w_ih_b,
    const float* __restrict__ b_ih_f, const float* __restrict__ b_hh_f,
    const float* __restrict__ b_ih_b, const float* __restrict__ b_hh_b,
    float* __restrict__ xg_f, float* __restrict__ xg_b)
{
    const int ng = blockIdx.x;   // 0..47
    const int mt = blockIdx.y;   // 0..7
    const int dir = blockIdx.z;  // 0..1
    const float* Wih = dir ? w_ih_b : w_ih_f;
    const float* BI  = dir ? b_ih_b : b_ih_f;
    const float* BH  = dir ? b_hh_b : b_hh_f;
    float* XG = dir ? xg_b : xg_f;

    const int tid = threadIdx.x;
    const int wave = tid >> 6, lane = tid & 63;
    // wave-uniform n-tile base -> scalar weight loads
    const int n0 = __builtin_amdgcn_readfirstlane((ng * 8 + wave) * 8);

    const int m = mt * 64 + lane;
    const int b = m >> 3, t = m & 7;
    const int tt = dir ? (7 - t) : t;
    const int row = idx[b * 8 + tt];
    const float4* ap = (const float4*)(electra + ((size_t)b * SEQ + row) * HID);

    const float4* w0 = (const float4*)(Wih + (size_t)(n0 + 0) * HID);
    const float4* w1 = (const float4*)(Wih + (size_t)(n0 + 1) * HID);
    const float4* w2 = (const float4*)(Wih + (size_t)(n0 + 2) * HID);
    const float4* w3 = (const float4*)(Wih + (size_t)(n0 + 3) * HID);
    const float4* w4 = (const float4*)(Wih + (size_t)(n0 + 4) * HID);
    const float4* w5 = (const float4*)(Wih + (size_t)(n0 + 5) * HID);
    const float4* w6 = (const float4*)(Wih + (size_t)(n0 + 6) * HID);
    const float4* w7 = (const float4*)(Wih + (size_t)(n0 + 7) * HID);

    float a0 = 0.f, a1 = 0.f, a2 = 0.f, a3 = 0.f;
    float a4 = 0.f, a5 = 0.f, a6 = 0.f, a7 = 0.f;
#pragma unroll 2
    for (int kt = 0; kt < HID / 4; ++kt) {
        const float4 a = ap[kt];
        const float4 q0 = w0[kt];
        a0 = fmaf(a.x, q0.x, fmaf(a.y, q0.y, fmaf(a.z, q0.z, fmaf(a.w, q0.w, a0))));
        const float4 q1 = w1[kt];
        a1 = fmaf(a.x, q1.x, fmaf(a.y, q1.y, fmaf(a.z, q1.z, fmaf(a.w, q1.w, a1))));
        const float4 q2 = w2[kt];
        a2 = fmaf(a.x, q2.x, fmaf(a.y, q2.y, fmaf(a.z, q2.z, fmaf(a.w, q2.w, a2))));
        const float4 q3 = w3[kt];
        a3 = fmaf(a.x, q3.x, fmaf(a.y, q3.y, fmaf(a.z, q3.z, fmaf(a.w, q3.w, a3))));
        const float4 q4 = w4[kt];
        a4 = fmaf(a.x, q4.x, fmaf(a.y, q4.y, fmaf(a.z, q4.z, fmaf(a.w, q4.w, a4))));
        const float4 q5 = w5[kt];
        a5 = fmaf(a.x, q5.x, fmaf(a.y, q5.y, fmaf(a.z, q5.z, fmaf(a.w, q5.w, a5))));
        const float4 q6 = w6[kt];
        a6 = fmaf(a.x, q6.x, fmaf(a.y, q6.y, fmaf(a.z, q6.z, fmaf(a.w, q6.w, a6))));
        const float4 q7 = w7[kt];
        a7 = fmaf(a.x, q7.x, fmaf(a.y, q7.y, fmaf(a.z, q7.z, fmaf(a.w, q7.w, a7))));
    }

    // bias (scalar) + coalesced stores into XG^T[n][m]
    float* outp = XG + (size_t)n0 * 512 + m;
    outp[0 * 512] = a0 + BI[n0 + 0] + BH[n0 + 0];
    outp[1 * 512] = a1 + BI[n0 + 1] + BH[n0 + 1];
    outp[2 * 512] = a2 + BI[n0 + 2] + BH[n0 + 2];
    outp[3 * 512] = a3 + BI[n0 + 3] + BH[n0 + 3];
    outp[4 * 512] = a4 + BI[n0 + 4] + BH[n0 + 4];
    outp[5 * 512] = a5 + BI[n0 + 5] + BH[n0 + 5];
    outp[6 * 512] = a6 + BI[n0 + 6] + BH[n0 + 6];
    outp[7 * 512] = a7 + BI[n0 + 7] + BH[n0 + 7];
}

// ---------------------------------------------------------------------------
// K3: one LSTM step (launched 8x). lane = batch, wave = (jslot 0..2, khalf).
// w_hh gate rows read via SCALAR float4 loads (wave-uniform bases, original
// layout, no packing); h via coalesced 256B/wave loads from hT[dir][k][b].
// K split over wave pairs; small LDS reduction. grid = 512 x 384 thr
// = 2 blocks/CU, 12 waves/CU, exact balance.
// ---------------------------------------------------------------------------
__global__ __launch_bounds__(384) void lstm_step_kernel(
    const float* __restrict__ whh_f, const float* __restrict__ whh_b,
    const float* __restrict__ xg_f, const float* __restrict__ xg_b,
    const float* __restrict__ hcur, float* __restrict__ hnext,
    float* __restrict__ c_state, float* __restrict__ HF, float* __restrict__ HL,
    int s)
{
    const int bid = blockIdx.x;
    const int dir = bid >> 8;          // 0..1
    const int rem = bid & 255;         // 0..255
    const int tid = threadIdx.x;
    const int wave = tid >> 6;         // 0..5
    const int lane = tid & 63;         // batch
    const int jslot = wave >> 1;       // 0..2
    const int kh = wave & 1;           // k-half
    const int j = rem * 3 + jslot;     // 0..767

    // wave-uniform scalar bases for the 4 gate rows of w_hh
    const float* WHH = dir ? whh_b : whh_f;
    const int jrow = __builtin_amdgcn_readfirstlane(j);
    const int kbase = __builtin_amdgcn_readfirstlane(kh * 384);
    const float4* wi = (const float4*)(WHH + (size_t)(0 * HID + jrow) * HID + kbase);
    const float4* wf = (const float4*)(WHH + (size_t)(1 * HID + jrow) * HID + kbase);
    const float4* wg = (const float4*)(WHH + (size_t)(2 * HID + jrow) * HID + kbase);
    const float4* wo = (const float4*)(WHH + (size_t)(3 * HID + jrow) * HID + kbase);
    const float* hp = hcur + ((size_t)dir * HID + kbase) * 64 + lane;

    float fi0 = 0.f, ff0 = 0.f, fg0 = 0.f, fo0 = 0.f;
    float fi1 = 0.f, ff1 = 0.f, fg1 = 0.f, fo1 = 0.f;
    if (s > 0) {
#pragma unroll 4
        for (int kt = 0; kt < 96; ++kt) {
            const float4 vi = wi[kt];
            const float4 vf = wf[kt];
            const float4 vg = wg[kt];
            const float4 vo = wo[kt];
            const float h0 = hp[(size_t)(kt * 4 + 0) * 64];
            const float h1 = hp[(size_t)(kt * 4 + 1) * 64];
            const float h2 = hp[(size_t)(kt * 4 + 2) * 64];
            const float h3 = hp[(size_t)(kt * 4 + 3) * 64];
            fi0 = fmaf(vi.x, h0, fmaf(vi.y, h1, fi0));
            fi1 = fmaf(vi.z, h2, fmaf(vi.w, h3, fi1));
            ff0 = fmaf(vf.x, h0, fmaf(vf.y, h1, ff0));
            ff1 = fmaf(vf.z, h2, fmaf(vf.w, h3, ff1));
            fg0 = fmaf(vg.x, h0, fmaf(vg.y, h1, fg0));
            fg1 = fmaf(vg.z, h2, fmaf(vg.w, h3, fg1));
            fo0 = fmaf(vo.x, h0, fmaf(vo.y, h1, fo0));
            fo1 = fmaf(vo.z, h2, fmaf(vo.w, h3, fo1));
        }
    }
    float fi = fi0 + fi1, ff = ff0 + ff1, fg = fg0 + fg1, fo = fo0 + fo1;

    __shared__ float red[2][3][4][64];
    red[kh][jslot][0][lane] = fi;
    red[kh][jslot][1][lane] = ff;
    red[kh][jslot][2][lane] = fg;
    red[kh][jslot][3][lane] = fo;
    __syncthreads();

    if (kh == 0) {
        fi += red[1][jslot][0][lane];
        ff += red[1][jslot][1][lane];
        fg += red[1][jslot][2][lane];
        fo += red[1][jslot][3][lane];

        // xg^T layout: [dir][n][m], n = g*HID + j, m = lane*8 + s
        const float* xgp = (dir ? xg_b : xg_f) + (size_t)j * 512 + lane * 8 + s;
        const float gi = sigmoid_(fi + xgp[0 * HID * 512]);
        const float gf = sigmoid_(ff + xgp[1 * HID * 512]);
        const float gg = tanhf (fg + xgp[2 * HID * 512]);
        const float go = sigmoid_(fo + xgp[3 * HID * 512]);

        const size_t slot = ((size_t)dir * HID + j) * 64 + lane;
        float c = (s == 0) ? 0.0f : c_state[slot];
        c = gf * c + gi * gg;
        c_state[slot] = c;
        const float hn = go * tanhf(c);
        hnext[slot] = hn;
        if (s == 0) HF[slot] = hn;
        if (s == 7) HL[slot] = hn;
    }
}

// ---------------------------------------------------------------------------
// K4: head. HF/HL layout: [dir][j][b].
// sep_first = [h_fwd(t0)=HF d0, h_bwd(t0)=HL d1]
// sep_last  = [h_fwd(t7)=HL d0, h_bwd(t7)=HF d1]
// ---------------------------------------------------------------------------
__device__ __forceinline__ void reduce10_(float* p, float* red, int tid,
                                          float* dst, const float* __restrict__ bias) {
#pragma unroll
    for (int o = 0; o < 10; ++o) {
        float v = p[o];
#pragma unroll
        for (int off = 32; off > 0; off >>= 1) v += __shfl_down(v, off);
        if ((tid & 63) == 0) red[o * 4 + (tid >> 6)] = v;
    }
    __syncthreads();
    if (tid < 10) dst[tid] = red[tid * 4 + 0] + red[tid * 4 + 1] + red[tid * 4 + 2] + red[tid * 4 + 3] + bias[tid];
    __syncthreads();
}

__global__ __launch_bounds__(256) void head_kernel(
    const float* __restrict__ electra, const float* __restrict__ HF,
    const float* __restrict__ HL,
    const float* __restrict__ fc1_w, const float* __restrict__ fc1_b,
    const float* __restrict__ fc2_w, const float* __restrict__ fc2_b,
    float* __restrict__ out)
{
    const int b = blockIdx.x;
    const int tid = threadIdx.x;
    __shared__ float xs[5 * HID];
    __shared__ float sf[2 * HID];
    __shared__ float sl[2 * HID];
    __shared__ float red[40];

    for (int k = tid; k < HID; k += 256) {
        xs[k] = gelu_(electra[(size_t)b * SEQ * HID + k]);          // cls row
        const float v1 = HF[(size_t)k * 64 + b];                    // fwd t0
        const float v2 = HL[((size_t)HID + k) * 64 + b];            // bwd t0 (scan step 7)
        const float v3 = HL[(size_t)k * 64 + b];                    // fwd t7
        const float v4 = HF[((size_t)HID + k) * 64 + b];            // bwd t7 (scan step 0)
        sf[k] = v1;        xs[HID + k]     = gelu_(v1);
        sf[HID + k] = v2;  xs[2 * HID + k] = gelu_(v2);
        sl[k] = v3;        xs[3 * HID + k] = gelu_(v3);
        sl[HID + k] = v4;  xs[4 * HID + k] = gelu_(v4);
    }
    __syncthreads();

    {
        float p[10];
#pragma unroll
        for (int o = 0; o < 10; ++o) p[o] = 0.f;
        for (int k = tid; k < 5 * HID; k += 256) {
            const float xv = xs[k];
#pragma unroll
            for (int o = 0; o < 10; ++o) p[o] = fmaf(xv, fc1_w[o * (5 * HID) + k], p[o]);
        }
        reduce10_(p, red, tid, out + b * 10, fc1_b);
    }
    {
        float p[10];
#pragma unroll
        for (int o = 0; o < 10; ++o) p[o] = 0.f;
        for (int k = tid; k < 2 * HID; k += 256) {
            const float v = sf[k];
#pragma unroll
            for (int o = 0; o < 10; ++o) p[o] = fmaf(v, fc2_w[o * (2 * HID) + k], p[o]);
        }
        reduce10_(p, red, tid, out + 640 + b * 10, fc2_b);
    }
    {
        float p[10];
#pragma unroll
        for (int o = 0; o < 10; ++o) p[o] = 0.f;
        for (int k = tid; k < 2 * HID; k += 256) {
            const float v = sl[k];
#pragma unroll
            for (int o = 0; o < 10; ++o) p[o] = fmaf(v, fc2_w[o * (2 * HID) + k], p[o]);
        }
        reduce10_(p, red, tid, out + 1280 + b * 10, fc2_b);
    }
}

// ---------------------------------------------------------------------------
extern "C" void kernel_launch(void* const* d_in, const int* in_sizes, int n_in,
                              void* d_out, int out_size, void* d_ws, size_t ws_size,
                              hipStream_t stream) {
    const float* electra = (const float*)d_in[0];
    const void*  sep_by  = d_in[2];
    const float* w_ih_f  = (const float*)d_in[3];
    const float* w_hh_f  = (const float*)d_in[4];
    const float* b_ih_f  = (const float*)d_in[5];
    const float* b_hh_f  = (const float*)d_in[6];
    const float* w_ih_b  = (const float*)d_in[7];
    const float* w_hh_b  = (const float*)d_in[8];
    const float* b_ih_b  = (const float*)d_in[9];
    const float* b_hh_b  = (const float*)d_in[10];
    const float* fc1_w   = (const float*)d_in[11];
    const float* fc1_b   = (const float*)d_in[12];
    const float* fc2_w   = (const float*)d_in[13];
    const float* fc2_b   = (const float*)d_in[14];
    float* out = (float*)d_out;

    // workspace layout (bytes): ~14.7 MB total
    char* ws = (char*)d_ws;
    int*   idx     = (int*)(ws);                          // 4 KB
    float* xg_f    = (float*)(ws + 4096);                 // 6.29 MB [3072][512]
    float* xg_b    = (float*)(ws + 4096 + 6291456);       // 6.29 MB
    char*  p2      = ws + 4096 + 2 * 6291456;
    float* hT      = (float*)(p2);                        // 786 KB: 2 parities x [2][768][64]
    float* c_state = (float*)(p2 + 786432);               // 384 KB [2][768][64]
    float* HF      = (float*)(p2 + 786432 + 393216);      // 384 KB
    float* HL      = (float*)(p2 + 786432 + 2 * 393216);  // 384 KB

    decode_idx_kernel<<<1, 512, 0, stream>>>(sep_by, NB * NL, idx);

    xg_gemm_kernel<<<dim3(48, 8, 2), 512, 0, stream>>>(
        electra, idx, w_ih_f, w_ih_b, b_ih_f, b_hh_f, b_ih_b, b_hh_b, xg_f, xg_b);

    const int PAR = 2 * HID * 64;   // floats per parity
    for (int s = 0; s < 8; ++s) {
        const float* hcur = hT + (s & 1) * PAR;
        float* hnext = hT + ((s + 1) & 1) * PAR;
        lstm_step_kernel<<<512, 384, 0, stream>>>(
            w_hh_f, w_hh_b, xg_f, xg_b, hcur, hnext, c_state, HF, HL, s);
    }

    head_kernel<<<64, 256, 0, stream>>>(electra, HF, HL,
                                        fc1_w, fc1_b, fc2_w, fc2_b, out);
}

// Round 8
// 448.029 us; speedup vs baseline: 1.9538x; 1.2110x over previous
//
#include <hip/hip_runtime.h>
#include <math.h>

#define HID 768
#define NB 64
#define NL 8
#define SEQ 512
#define G4 3072    // 4*HID
#define MTOT 512   // NB*NL

__device__ __forceinline__ float sigmoid_(float x) { return 1.0f / (1.0f + expf(-x)); }
__device__ __forceinline__ float gelu_(float x) { return 0.5f * x * (1.0f + erff(x * 0.70710678118654752440f)); }

// ---------------------------------------------------------------------------
// K1: decode sep_by indices (handles int64 or int32 payload)
// ---------------------------------------------------------------------------
__global__ void decode_idx_kernel(const void* __restrict__ sep_by, int n, int* __restrict__ out) {
    const int* p32 = (const int*)sep_by;
    const bool is64 = (p32[1] == 0) && (p32[3] == 0) && (p32[5] == 0) && (p32[7] == 0);
    int i = blockIdx.x * blockDim.x + threadIdx.x;
    if (i < n) {
        out[i] = is64 ? (int)((const long long*)sep_by)[i] : p32[i];
    }
}

// ---------------------------------------------------------------------------
// K2a: gather + transpose: GT[dir][k][m], m = b*8+t (scan order; dir=1 gathers
// time-reversed rows). 64x64 LDS tile; reads and writes fully coalesced.
// ---------------------------------------------------------------------------
__global__ __launch_bounds__(256) void gatherT_kernel(
    const float* __restrict__ electra, const int* __restrict__ idx,
    float* __restrict__ GT)   // [2][768][512]
{
    const int kt = blockIdx.x;   // 0..11
    const int mt = blockIdx.y;   // 0..7
    const int dir = blockIdx.z;  // 0..1
    __shared__ float T[64][65];
    const int t = threadIdx.x;
    const int k0 = kt * 64, m0 = mt * 64;
#pragma unroll
    for (int i = 0; i < 4; ++i) {
        const int f4i = i * 256 + t;
        const int ml = f4i >> 4;       // 0..63
        const int k16 = f4i & 15;      // 0..15
        const int m = m0 + ml;
        const int b = m >> 3, ts0 = m & 7;
        const int ts = dir ? (7 - ts0) : ts0;
        const int row = idx[b * 8 + ts];
        const float4 v = *(const float4*)(electra + ((size_t)b * SEQ + row) * HID + k0 + k16 * 4);
        T[ml][k16 * 4 + 0] = v.x; T[ml][k16 * 4 + 1] = v.y;
        T[ml][k16 * 4 + 2] = v.z; T[ml][k16 * 4 + 3] = v.w;
    }
    __syncthreads();
#pragma unroll
    for (int i = 0; i < 4; ++i) {
        const int f4i = i * 256 + t;
        const int kl = f4i >> 4;       // 0..63
        const int m16 = f4i & 15;      // 0..15
        float4 v;
        v.x = T[m16 * 4 + 0][kl]; v.y = T[m16 * 4 + 1][kl];
        v.z = T[m16 * 4 + 2][kl]; v.w = T[m16 * 4 + 3][kl];
        *(float4*)(GT + ((size_t)dir * HID + k0 + kl) * MTOT + m0 + m16 * 4) = v;
    }
}

// ---------------------------------------------------------------------------
// K2b: transpose w_ih: WT[dir][k][n] from w_ih[n][k]. Same tile scheme.
// ---------------------------------------------------------------------------
__global__ __launch_bounds__(256) void transposeW_kernel(
    const float* __restrict__ w_ih_f, const float* __restrict__ w_ih_b,
    float* __restrict__ WT)   // [2][768][3072]
{
    const int kt = blockIdx.x;   // 0..11
    const int nt = blockIdx.y;   // 0..47
    const int dir = blockIdx.z;
    const float* W = dir ? w_ih_b : w_ih_f;
    __shared__ float T[64][65];
    const int t = threadIdx.x;
    const int k0 = kt * 64, n0 = nt * 64;
#pragma unroll
    for (int i = 0; i < 4; ++i) {
        const int f4i = i * 256 + t;
        const int nl = f4i >> 4;
        const int k16 = f4i & 15;
        const float4 v = *(const float4*)(W + (size_t)(n0 + nl) * HID + k0 + k16 * 4);
        T[nl][k16 * 4 + 0] = v.x; T[nl][k16 * 4 + 1] = v.y;
        T[nl][k16 * 4 + 2] = v.z; T[nl][k16 * 4 + 3] = v.w;
    }
    __syncthreads();
#pragma unroll
    for (int i = 0; i < 4; ++i) {
        const int f4i = i * 256 + t;
        const int kl = f4i >> 4;
        const int n16 = f4i & 15;
        float4 v;
        v.x = T[n16 * 4 + 0][kl]; v.y = T[n16 * 4 + 1][kl];
        v.z = T[n16 * 4 + 2][kl]; v.w = T[n16 * 4 + 3][kl];
        *(float4*)(WT + ((size_t)dir * HID + k0 + kl) * G4 + n0 + n16 * 4) = v;
    }
}

// ---------------------------------------------------------------------------
// K3: xg GEMM. C[m][n] = GT^T . WT + bias -> xg[dir][n][m].
// 128x128 tile, BK=16, 256 thr, 8x8/thread, reg-double-buffered staging.
// grid = 24 x 4 x 2 = 192 blocks.
// ---------------------------------------------------------------------------
__global__ __launch_bounds__(256) void xg_gemm_kernel(
    const float* __restrict__ GT, const float* __restrict__ WT,
    const float* __restrict__ b_ih_f, const float* __restrict__ b_hh_f,
    const float* __restrict__ b_ih_b, const float* __restrict__ b_hh_b,
    float* __restrict__ xg)   // [2][3072][512]
{
    const int nt = blockIdx.x;   // 0..23
    const int mt = blockIdx.y;   // 0..3
    const int dir = blockIdx.z;
    const float* BI = dir ? b_ih_b : b_ih_f;
    const float* BH = dir ? b_hh_b : b_hh_f;
    const float* gt = GT + (size_t)dir * HID * MTOT;
    const float* wt = WT + (size_t)dir * HID * G4;
    const int n0 = nt * 128, m0 = mt * 128;

    __shared__ float As[16][128];
    __shared__ float Ws[16][128];

    const int t = threadIdx.x;
    const int tx = t & 15, ty = t >> 4;
    const int k1 = t >> 5;            // 0..7
    const int k2 = 8 + (t >> 5);      // 8..15
    const int m4 = t & 31;            // 0..31

    float4 ra0, ra1, rw0, rw1;
    ra0 = *(const float4*)(gt + (size_t)k1 * MTOT + m0 + m4 * 4);
    ra1 = *(const float4*)(gt + (size_t)k2 * MTOT + m0 + m4 * 4);
    rw0 = *(const float4*)(wt + (size_t)k1 * G4 + n0 + m4 * 4);
    rw1 = *(const float4*)(wt + (size_t)k2 * G4 + n0 + m4 * 4);

    float acc[8][8] = {};
    for (int c = 0; c < 48; ++c) {
        *(float4*)&As[k1][m4 * 4] = ra0;
        *(float4*)&As[k2][m4 * 4] = ra1;
        *(float4*)&Ws[k1][m4 * 4] = rw0;
        *(float4*)&Ws[k2][m4 * 4] = rw1;
        __syncthreads();
        if (c < 47) {
            const int kb = (c + 1) * 16;
            ra0 = *(const float4*)(gt + (size_t)(kb + k1) * MTOT + m0 + m4 * 4);
            ra1 = *(const float4*)(gt + (size_t)(kb + k2) * MTOT + m0 + m4 * 4);
            rw0 = *(const float4*)(wt + (size_t)(kb + k1) * G4 + n0 + m4 * 4);
            rw1 = *(const float4*)(wt + (size_t)(kb + k2) * G4 + n0 + m4 * 4);
        }
#pragma unroll
        for (int k = 0; k < 16; ++k) {
            float a[8], bb[8];
            *(float4*)&a[0]  = *(const float4*)&As[k][ty * 8];
            *(float4*)&a[4]  = *(const float4*)&As[k][ty * 8 + 4];
            *(float4*)&bb[0] = *(const float4*)&Ws[k][tx * 8];
            *(float4*)&bb[4] = *(const float4*)&Ws[k][tx * 8 + 4];
#pragma unroll
            for (int i = 0; i < 8; ++i)
#pragma unroll
                for (int j2 = 0; j2 < 8; ++j2)
                    acc[i][j2] = fmaf(a[i], bb[j2], acc[i][j2]);
        }
        __syncthreads();
    }

    float* xgd = xg + (size_t)dir * G4 * MTOT;
#pragma unroll
    for (int j2 = 0; j2 < 8; ++j2) {
        const int n = n0 + tx * 8 + j2;
        const float bias = BI[n] + BH[n];
        float4 o0, o1;
        o0.x = acc[0][j2] + bias; o0.y = acc[1][j2] + bias;
        o0.z = acc[2][j2] + bias; o0.w = acc[3][j2] + bias;
        o1.x = acc[4][j2] + bias; o1.y = acc[5][j2] + bias;
        o1.z = acc[6][j2] + bias; o1.w = acc[7][j2] + bias;
        *(float4*)(xgd + (size_t)n * MTOT + m0 + ty * 8)     = o0;
        *(float4*)(xgd + (size_t)n * MTOT + m0 + ty * 8 + 4) = o1;
    }
}

// ---------------------------------------------------------------------------
// K4: one LSTM step (launched 8x). Block owns (dir, 3 j's): stages its 12
// w_hh gate-rows (36.9 KB) into LDS once (coalesced), then the k-loop reads
// weights as LDS broadcasts (wave-uniform addr, conflict-free) and h as
// packed float4 (layout h4[dir][k/4][b][4] -> 1024B/wave coalesced, 4 k's
// per VMEM instr). grid = dim3(256, 2) = 512 blocks x 256 thr = 2 blocks/CU.
// ---------------------------------------------------------------------------
__global__ __launch_bounds__(256) void lstm_step_kernel(
    const float* __restrict__ whh_f, const float* __restrict__ whh_b,
    const float* __restrict__ xg,    // [2][3072][512]
    const float* __restrict__ hcur,  // packed [2][192][64][4]
    float* __restrict__ hnext,       // packed [2][192][64][4]
    float* __restrict__ c_state, float* __restrict__ HF, float* __restrict__ HL,
    int s)
{
    const int jg = blockIdx.x;       // 0..255
    const int dir = blockIdx.y;      // 0..1
    const float* WHH = dir ? whh_b : whh_f;
    const int t = threadIdx.x;

    __shared__ float Wl[12][768];    // rows r = jl*4 + g
    __shared__ float red[12][64];

#pragma unroll
    for (int i = 0; i < 9; ++i) {
        const int f4i = i * 256 + t;       // 0..2303
        const int r = f4i / 192;           // 0..11
        const int k4 = f4i % 192;
        const int jl = r >> 2, g = r & 3;
        const int grow = g * HID + jg * 3 + jl;
        *(float4*)&Wl[r][k4 * 4] = *(const float4*)(WHH + (size_t)grow * HID + k4 * 4);
    }
    __syncthreads();

    const int wave = t >> 6, lane = t & 63;   // lane = batch
    const int r0 = wave * 3;                   // rows r0..r0+2
    const float4* hp = (const float4*)hcur + (size_t)dir * 192 * 64 + lane;
    float acc0 = 0.f, acc1 = 0.f, acc2 = 0.f;
    if (s > 0) {
#pragma unroll 4
        for (int k4 = 0; k4 < 192; ++k4) {
            const float4 h = hp[(size_t)k4 * 64];
            const float4 w0 = *(const float4*)&Wl[r0 + 0][k4 * 4];
            const float4 w1 = *(const float4*)&Wl[r0 + 1][k4 * 4];
            const float4 w2 = *(const float4*)&Wl[r0 + 2][k4 * 4];
            acc0 = fmaf(w0.x, h.x, fmaf(w0.y, h.y, fmaf(w0.z, h.z, fmaf(w0.w, h.w, acc0))));
            acc1 = fmaf(w1.x, h.x, fmaf(w1.y, h.y, fmaf(w1.z, h.z, fmaf(w1.w, h.w, acc1))));
            acc2 = fmaf(w2.x, h.x, fmaf(w2.y, h.y, fmaf(w2.z, h.z, fmaf(w2.w, h.w, acc2))));
        }
    }
    red[r0 + 0][lane] = acc0;
    red[r0 + 1][lane] = acc1;
    red[r0 + 2][lane] = acc2;
    __syncthreads();

    if (t < 192) {
        const int jl = t >> 6;      // 0..2
        const int b = t & 63;
        const int j = jg * 3 + jl;
        const float fi = red[jl * 4 + 0][b];
        const float ff = red[jl * 4 + 1][b];
        const float fg = red[jl * 4 + 2][b];
        const float fo = red[jl * 4 + 3][b];
        const float* xgp = xg + (size_t)dir * G4 * MTOT + (size_t)j * MTOT + b * 8 + s;
        const float gi = sigmoid_(fi + xgp[0]);
        const float gf = sigmoid_(ff + xgp[(size_t)1 * HID * MTOT]);
        const float gg = tanhf (fg + xgp[(size_t)2 * HID * MTOT]);
        const float go = sigmoid_(fo + xgp[(size_t)3 * HID * MTOT]);

        const size_t slot = ((size_t)dir * HID + j) * 64 + b;
        float c = (s == 0) ? 0.0f : c_state[slot];
        c = gf * c + gi * gg;
        c_state[slot] = c;
        const float hn = go * tanhf(c);
        // packed h write: [dir][j>>2][b][j&3]
        hnext[(((size_t)dir * 192 + (j >> 2)) * 64 + b) * 4 + (j & 3)] = hn;
        if (s == 0) HF[slot] = hn;
        if (s == 7) HL[slot] = hn;
    }
}

// ---------------------------------------------------------------------------
// K5: head. HF/HL layout: [dir*HID + j][b].
// sep_first = [h_fwd(t0)=HF d0, h_bwd(t0)=HL d1]
// sep_last  = [h_fwd(t7)=HL d0, h_bwd(t7)=HF d1]
// ---------------------------------------------------------------------------
__device__ __forceinline__ void reduce10_(float* p, float* red, int tid,
                                          float* dst, const float* __restrict__ bias) {
#pragma unroll
    for (int o = 0; o < 10; ++o) {
        float v = p[o];
#pragma unroll
        for (int off = 32; off > 0; off >>= 1) v += __shfl_down(v, off);
        if ((tid & 63) == 0) red[o * 4 + (tid >> 6)] = v;
    }
    __syncthreads();
    if (tid < 10) dst[tid] = red[tid * 4 + 0] + red[tid * 4 + 1] + red[tid * 4 + 2] + red[tid * 4 + 3] + bias[tid];
    __syncthreads();
}

__global__ __launch_bounds__(256) void head_kernel(
    const float* __restrict__ electra, const float* __restrict__ HF,
    const float* __restrict__ HL,
    const float* __restrict__ fc1_w, const float* __restrict__ fc1_b,
    const float* __restrict__ fc2_w, const float* __restrict__ fc2_b,
    float* __restrict__ out)
{
    const int b = blockIdx.x;
    const int tid = threadIdx.x;
    __shared__ float xs[5 * HID];
    __shared__ float sf[2 * HID];
    __shared__ float sl[2 * HID];
    __shared__ float red[40];

    for (int k = tid; k < HID; k += 256) {
        xs[k] = gelu_(electra[(size_t)b * SEQ * HID + k]);          // cls row
        const float v1 = HF[(size_t)k * 64 + b];                    // fwd t0
        const float v2 = HL[((size_t)HID + k) * 64 + b];            // bwd t0 (scan step 7)
        const float v3 = HL[(size_t)k * 64 + b];                    // fwd t7
        const float v4 = HF[((size_t)HID + k) * 64 + b];            // bwd t7 (scan step 0)
        sf[k] = v1;        xs[HID + k]     = gelu_(v1);
        sf[HID + k] = v2;  xs[2 * HID + k] = gelu_(v2);
        sl[k] = v3;        xs[3 * HID + k] = gelu_(v3);
        sl[HID + k] = v4;  xs[4 * HID + k] = gelu_(v4);
    }
    __syncthreads();

    {
        float p[10];
#pragma unroll
        for (int o = 0; o < 10; ++o) p[o] = 0.f;
        for (int k = tid; k < 5 * HID; k += 256) {
            const float xv = xs[k];
#pragma unroll
            for (int o = 0; o < 10; ++o) p[o] = fmaf(xv, fc1_w[o * (5 * HID) + k], p[o]);
        }
        reduce10_(p, red, tid, out + b * 10, fc1_b);
    }
    {
        float p[10];
#pragma unroll
        for (int o = 0; o < 10; ++o) p[o] = 0.f;
        for (int k = tid; k < 2 * HID; k += 256) {
            const float v = sf[k];
#pragma unroll
            for (int o = 0; o < 10; ++o) p[o] = fmaf(v, fc2_w[o * (2 * HID) + k], p[o]);
        }
        reduce10_(p, red, tid, out + 640 + b * 10, fc2_b);
    }
    {
        float p[10];
#pragma unroll
        for (int o = 0; o < 10; ++o) p[o] = 0.f;
        for (int k = tid; k < 2 * HID; k += 256) {
            const float v = sl[k];
#pragma unroll
            for (int o = 0; o < 10; ++o) p[o] = fmaf(v, fc2_w[o * (2 * HID) + k], p[o]);
        }
        reduce10_(p, red, tid, out + 1280 + b * 10, fc2_b);
    }
}

// ---------------------------------------------------------------------------
extern "C" void kernel_launch(void* const* d_in, const int* in_sizes, int n_in,
                              void* d_out, int out_size, void* d_ws, size_t ws_size,
                              hipStream_t stream) {
    const float* electra = (const float*)d_in[0];
    const void*  sep_by  = d_in[2];
    const float* w_ih_f  = (const float*)d_in[3];
    const float* w_hh_f  = (const float*)d_in[4];
    const float* b_ih_f  = (const float*)d_in[5];
    const float* b_hh_f  = (const float*)d_in[6];
    const float* w_ih_b  = (const float*)d_in[7];
    const float* w_hh_b  = (const float*)d_in[8];
    const float* b_ih_b  = (const float*)d_in[9];
    const float* b_hh_b  = (const float*)d_in[10];
    const float* fc1_w   = (const float*)d_in[11];
    const float* fc1_b   = (const float*)d_in[12];
    const float* fc2_w   = (const float*)d_in[13];
    const float* fc2_b   = (const float*)d_in[14];
    float* out = (float*)d_out;

    // workspace layout (bytes): ~36.6 MB
    char* ws = (char*)d_ws;
    int*   idx     = (int*)(ws);                    // 4 KB
    float* GT      = (float*)(ws + 4096);           // 3,145,728  [2][768][512]
    float* WT      = (float*)(ws + 3149824);        // 18,874,368 [2][768][3072]
    float* XG      = (float*)(ws + 22024192);       // 12,582,912 [2][3072][512]
    float* hT      = (float*)(ws + 34607104);       // 786,432 : 2 par x packed [2][192][64][4]
    float* c_state = (float*)(ws + 35393536);       // 393,216
    float* HF      = (float*)(ws + 35786752);       // 393,216
    float* HL      = (float*)(ws + 36179968);       // 393,216

    decode_idx_kernel<<<1, 512, 0, stream>>>(sep_by, NB * NL, idx);

    gatherT_kernel<<<dim3(12, 8, 2), 256, 0, stream>>>(electra, idx, GT);
    transposeW_kernel<<<dim3(12, 48, 2), 256, 0, stream>>>(w_ih_f, w_ih_b, WT);

    xg_gemm_kernel<<<dim3(24, 4, 2), 256, 0, stream>>>(
        GT, WT, b_ih_f, b_hh_f, b_ih_b, b_hh_b, XG);

    const int PAR = 2 * HID * 64;   // floats per parity (= 2*192*64*4)
    for (int s = 0; s < 8; ++s) {
        const float* hcur = hT + (s & 1) * PAR;
        float* hnext = hT + ((s + 1) & 1) * PAR;
        lstm_step_kernel<<<dim3(256, 2), 256, 0, stream>>>(
            w_hh_f, w_hh_b, XG, hcur, hnext, c_state, HF, HL, s);
    }

    head_kernel<<<64, 256, 0, stream>>>(electra, HF, HL,
                                        fc1_w, fc1_b, fc2_w, fc2_b, out);
}